// Round 13
// baseline (776.049 us; speedup 1.0000x reference)
//
#include <hip/hip_runtime.h>

#define NN 50000
#define EE 200000
#define BB 256
#define LL 1000

static inline int cdiv(int a, int b){ return (a + b - 1) / b; }

typedef __attribute__((ext_vector_type(4))) float f32x4;
typedef __attribute__((ext_vector_type(2))) float f32x2;
typedef __attribute__((ext_vector_type(8))) short bf16x8;

__device__ inline short f2bf(float f){
  unsigned u = __float_as_uint(f);
  unsigned r = u + 0x7fffu + ((u >> 16) & 1u);
  return (short)(r >> 16);
}
__device__ inline float bf2f(short s){
  return __uint_as_float(((unsigned)(unsigned short)s) << 16);
}

// ---------------- utility ----------------
__global__ void zero_kernel(unsigned* __restrict__ p, long n){
  long i = (long)blockIdx.x*blockDim.x + threadIdx.x;
  long st = (long)gridDim.x*blockDim.x;
  for(; i < n; i += st) p[i] = 0u;
}

// ---------------- small GEMM, direct ----------------
template<int ACT>
__global__ __launch_bounds__(256) void gemm_small_kernel(
    const float* __restrict__ A, const float* __restrict__ B,
    const float* __restrict__ bias, float* __restrict__ C,
    int M, int N, int K, int ldc){
  __shared__ float As[32][17];
  const int tid = threadIdx.x;
  const int col = blockIdx.x*64 + (tid & 63);
  const int rg = tid >> 6;
  const int row0 = blockIdx.y*32;
  float acc[8] = {};
  for(int kb = 0; kb < K; kb += 16){
    int kn = min(16, K - kb);
    for(int i = tid; i < 32*16; i += 256){
      int r = i >> 4, kk = i & 15;
      int gr = row0 + r;
      As[r][kk] = (gr < M && kb + kk < K) ? A[(long)gr*K + kb + kk] : 0.f;
    }
    __syncthreads();
    if(col < N){
      for(int kk = 0; kk < kn; kk++){
        float b = B[(long)(kb+kk)*N + col];
        #pragma unroll
        for(int i = 0; i < 8; i++)
          acc[i] = fmaf(As[rg*8 + i][kk], b, acc[i]);
      }
    }
    __syncthreads();
  }
  if(col < N){
    float bs = bias[col];
    #pragma unroll
    for(int i = 0; i < 8; i++){
      int r = row0 + rg*8 + i;
      if(r < M){
        float v = acc[i] + bs;
        if(ACT == 1) v = fmaxf(v, 0.f);
        C[(long)r*ldc + col] = v;
      }
    }
  }
}

// ---------------- split-K small GEMM ----------------
__global__ __launch_bounds__(256) void gemm_splitk_kernel(
    const float* __restrict__ A, const float* __restrict__ B,
    float* __restrict__ part, int M, int N, int K, int KS){
  __shared__ float As[32][17];
  const int tid = threadIdx.x;
  const int col = blockIdx.x*64 + (tid & 63);
  const int rg = tid >> 6;
  const int row0 = blockIdx.y*32;
  const int kc = (K + KS - 1) / KS;
  const int k0 = blockIdx.z * kc;
  const int k1 = min(k0 + kc, K);
  float acc[8] = {};
  for(int kb = k0; kb < k1; kb += 16){
    int kn = min(16, k1 - kb);
    for(int i = tid; i < 32*16; i += 256){
      int r = i >> 4, kk = i & 15;
      int gr = row0 + r;
      As[r][kk] = (gr < M && kb + kk < k1) ? A[(long)gr*K + kb + kk] : 0.f;
    }
    __syncthreads();
    if(col < N){
      for(int kk = 0; kk < kn; kk++){
        float b = B[(long)(kb+kk)*N + col];
        #pragma unroll
        for(int i = 0; i < 8; i++)
          acc[i] = fmaf(As[rg*8 + i][kk], b, acc[i]);
      }
    }
    __syncthreads();
  }
  if(col < N){
    #pragma unroll
    for(int i = 0; i < 8; i++){
      int r = row0 + rg*8 + i;
      if(r < M) part[((long)blockIdx.z*M + r)*N + col] = acc[i];
    }
  }
}

template<int ACT>
__global__ void splitk_reduce_kernel(const float* __restrict__ part,
                                     const float* __restrict__ bias,
                                     float* __restrict__ C,
                                     int M, int N, int KS, int ldc){
  int idx = blockIdx.x*256 + threadIdx.x;
  if(idx >= M*N) return;
  int r = idx / N, c = idx - r*N;
  float s = 0.f;
  for(int z = 0; z < KS; z++) s += part[((long)z*M + r)*N + c];
  s += bias[c];
  if(ACT == 1) s = fmaxf(s, 0.f);
  C[(long)r*ldc + c] = s;
}

// ---------------- MFMA bf16 GEMM, fp32 A input, bf16 output ----------------
__global__ __launch_bounds__(256) void gemm_mfma_bf16_kernel(
    const float* __restrict__ A, const float* __restrict__ B,
    short* __restrict__ C, int M, int N, int K, int ldc){
  __shared__ short As[128*32];
  __shared__ short Bs[64*32];
  const int tid = threadIdx.x;
  const int wave = tid >> 6, lane = tid & 63;
  const int wm = wave >> 1, wn = wave & 1;
  const int row0 = blockIdx.y*128, col0 = blockIdx.x*64;
  const int lrow = lane & 15;
  const int kslot = lane >> 4;
  const int bn = tid & 63, bs = tid >> 6;
  f32x4 acc[4][2] = {};
  for(int k0 = 0; k0 < K; k0 += 32){
    #pragma unroll
    for(int id = tid; id < 512; id += 256){
      int r = id >> 2, s = id & 3;
      int grow = row0 + r, gk = k0 + s*8;
      short vs[8];
      if(grow < M && gk + 7 < K){
        const float* p = A + (long)grow*K + gk;
        #pragma unroll
        for(int i = 0; i < 8; i += 2){
          f32x2 x = *(const f32x2*)(p + i);
          vs[i] = f2bf(x.x); vs[i+1] = f2bf(x.y);
        }
      } else {
        #pragma unroll
        for(int i = 0; i < 8; i++){
          float f = (grow < M && gk + i < K) ? A[(long)grow*K + gk + i] : 0.f;
          vs[i] = f2bf(f);
        }
      }
      *(bf16x8*)&As[r*32 + (s ^ ((r>>1)&3))*8] = *(const bf16x8*)vs;
    }
    {
      int gn = col0 + bn, gk = k0 + bs*8;
      short vs[8];
      #pragma unroll
      for(int i = 0; i < 8; i++){
        float f = (gn < N && gk + i < K) ? B[(long)(gk+i)*N + gn] : 0.f;
        vs[i] = f2bf(f);
      }
      *(bf16x8*)&Bs[bn*32 + (bs ^ ((bn>>1)&3))*8] = *(const bf16x8*)vs;
    }
    __syncthreads();
    bf16x8 af[4], bfr[2];
    #pragma unroll
    for(int mt = 0; mt < 4; mt++){
      int r = wm*64 + mt*16 + lrow;
      af[mt] = *(const bf16x8*)&As[r*32 + (kslot ^ ((r>>1)&3))*8];
    }
    #pragma unroll
    for(int nt = 0; nt < 2; nt++){
      int r = wn*32 + nt*16 + lrow;
      bfr[nt] = *(const bf16x8*)&Bs[r*32 + (kslot ^ ((r>>1)&3))*8];
    }
    #pragma unroll
    for(int mt = 0; mt < 4; mt++)
      #pragma unroll
      for(int nt = 0; nt < 2; nt++)
        acc[mt][nt] = __builtin_amdgcn_mfma_f32_16x16x32_bf16(af[mt], bfr[nt], acc[mt][nt], 0, 0, 0);
    __syncthreads();
  }
  #pragma unroll
  for(int mt = 0; mt < 4; mt++){
    #pragma unroll
    for(int nt = 0; nt < 2; nt++){
      #pragma unroll
      for(int rg = 0; rg < 4; rg++){
        int row = row0 + wm*64 + mt*16 + (lane>>4)*4 + rg;
        int col = col0 + wn*32 + nt*16 + (lane&15);
        if(row < M && col < N)
          C[(long)row*ldc + col] = f2bf(acc[mt][nt][rg]);
      }
    }
  }
}

// ---------------- MFMA bf16 GEMM, bf16 A input ----------------
__global__ __launch_bounds__(256) void gemm_mfma_bf16in_kernel(
    const short* __restrict__ A, int lda, const float* __restrict__ B,
    short* __restrict__ C, int M, int N, int K, int ldc){
  __shared__ short As[128*32];
  __shared__ short Bs[64*32];
  const int tid = threadIdx.x;
  const int wave = tid >> 6, lane = tid & 63;
  const int wm = wave >> 1, wn = wave & 1;
  const int row0 = blockIdx.y*128, col0 = blockIdx.x*64;
  const int lrow = lane & 15;
  const int kslot = lane >> 4;
  const int bn = tid & 63, bs = tid >> 6;
  f32x4 acc[4][2] = {};
  for(int k0 = 0; k0 < K; k0 += 32){
    #pragma unroll
    for(int id = tid; id < 512; id += 256){
      int r = id >> 2, s = id & 3;
      int grow = row0 + r, gk = k0 + s*8;
      short vs[8];
      if(grow < M && gk + 7 < K){
        *(bf16x8*)vs = *(const bf16x8*)&A[(long)grow*lda + gk];
      } else {
        #pragma unroll
        for(int i = 0; i < 8; i++)
          vs[i] = (grow < M && gk + i < K) ? A[(long)grow*lda + gk + i] : (short)0;
      }
      *(bf16x8*)&As[r*32 + (s ^ ((r>>1)&3))*8] = *(const bf16x8*)vs;
    }
    {
      int gn = col0 + bn, gk = k0 + bs*8;
      short vs[8];
      #pragma unroll
      for(int i = 0; i < 8; i++){
        float f = (gn < N && gk + i < K) ? B[(long)(gk+i)*N + gn] : 0.f;
        vs[i] = f2bf(f);
      }
      *(bf16x8*)&Bs[bn*32 + (bs ^ ((bn>>1)&3))*8] = *(const bf16x8*)vs;
    }
    __syncthreads();
    bf16x8 af[4], bfr[2];
    #pragma unroll
    for(int mt = 0; mt < 4; mt++){
      int r = wm*64 + mt*16 + lrow;
      af[mt] = *(const bf16x8*)&As[r*32 + (kslot ^ ((r>>1)&3))*8];
    }
    #pragma unroll
    for(int nt = 0; nt < 2; nt++){
      int r = wn*32 + nt*16 + lrow;
      bfr[nt] = *(const bf16x8*)&Bs[r*32 + (kslot ^ ((r>>1)&3))*8];
    }
    #pragma unroll
    for(int mt = 0; mt < 4; mt++)
      #pragma unroll
      for(int nt = 0; nt < 2; nt++)
        acc[mt][nt] = __builtin_amdgcn_mfma_f32_16x16x32_bf16(af[mt], bfr[nt], acc[mt][nt], 0, 0, 0);
    __syncthreads();
  }
  #pragma unroll
  for(int mt = 0; mt < 4; mt++){
    #pragma unroll
    for(int nt = 0; nt < 2; nt++){
      #pragma unroll
      for(int rg = 0; rg < 4; rg++){
        int row = row0 + wm*64 + mt*16 + (lane>>4)*4 + rg;
        int col = col0 + wn*32 + nt*16 + (lane&15);
        if(row < M && col < N)
          C[(long)row*ldc + col] = f2bf(acc[mt][nt][rg]);
      }
    }
  }
}

// Build WEXT[K][F+2H] = [W | interleaved Wa_src,Wa_dst columns]
__global__ void wext_kernel(const float* __restrict__ W, const float* __restrict__ asrc,
                            const float* __restrict__ adst, float* __restrict__ WEXT,
                            int K, int F, int H, int D){
  int NE = F + 2*H;
  int t = blockIdx.x*blockDim.x + threadIdx.x;
  if(t >= K*NE) return;
  int k = t / NE, c = t - k*NE;
  float v;
  if(c < F){
    v = W[(long)k*F + c];
  } else {
    int cc = c - F;
    int h = cc >> 1;
    const float* a = (cc & 1) ? (adst + h*D) : (asrc + h*D);
    const float* wr = W + (long)k*F + h*D;
    float s = 0.f;
    for(int d = 0; d < D; d++) s = fmaf(wr[d], a[d], s);
    v = s;
  }
  WEXT[t] = v;
}

__global__ void extract_scores_kernel(const short* __restrict__ HB, float* __restrict__ SS,
                                      float* __restrict__ SD, int N, int H, int F, int ldh){
  int t = blockIdx.x*blockDim.x + threadIdx.x;
  if(t >= N*H) return;
  int n = t / H, hh = t - n*H;
  const short* p = HB + (long)n*ldh + F + 2*hh;
  SS[t] = bf2f(p[0]);
  SD[t] = bf2f(p[1]);
}

// ---------------- CSR build ----------------
__global__ void count_kernel(const int* __restrict__ dst, int* __restrict__ deg, int E, int N){
  int e = blockIdx.x*blockDim.x + threadIdx.x;
  if(e >= E + N) return;
  int d = (e < E) ? dst[e] : (e - E);
  atomicAdd(&deg[d], 1);
}

__global__ void scan_sums_kernel(const int* __restrict__ deg, int* __restrict__ bsum, int n){
  __shared__ int red[256];
  int base = blockIdx.x*1024 + threadIdx.x*4;
  int s = 0;
  #pragma unroll
  for(int i = 0; i < 4; i++){ int idx = base + i; if(idx < n) s += deg[idx]; }
  red[threadIdx.x] = s;
  __syncthreads();
  for(int off = 128; off >= 1; off >>= 1){
    if((int)threadIdx.x < off) red[threadIdx.x] += red[threadIdx.x + off];
    __syncthreads();
  }
  if(threadIdx.x == 0) bsum[blockIdx.x] = red[0];
}

__global__ void scan_bsum_kernel(int* __restrict__ bsum, int nb){
  int lane = threadIdx.x;
  int v = (lane < nb) ? bsum[lane] : 0;
  for(int off = 1; off < 64; off <<= 1){
    int t = __shfl_up(v, off, 64);
    if(lane >= off) v += t;
  }
  int ex = __shfl_up(v, 1, 64);
  if(lane == 0) ex = 0;
  if(lane < nb) bsum[lane] = ex;
}

__global__ void scan_final_kernel(const int* __restrict__ deg, const int* __restrict__ bsum,
                                  int* __restrict__ indptr, int* __restrict__ cursor, int n){
  __shared__ int red[256];
  const int t = threadIdx.x;
  int base = blockIdx.x*1024 + t*4;
  int v[4]; int s = 0;
  #pragma unroll
  for(int i = 0; i < 4; i++){ int idx = base + i; v[i] = (idx < n) ? deg[idx] : 0; s += v[i]; }
  red[t] = s;
  __syncthreads();
  for(int off = 1; off < 256; off <<= 1){
    int val = (t >= off) ? red[t - off] : 0;
    __syncthreads();
    red[t] += val;
    __syncthreads();
  }
  int run = bsum[blockIdx.x] + ((t > 0) ? red[t-1] : 0);
  #pragma unroll
  for(int i = 0; i < 4; i++){
    int idx = base + i;
    if(idx < n){
      cursor[idx] = run;
      run += v[i];
      indptr[idx+1] = run;
    }
  }
  if(blockIdx.x == 0 && t == 0) indptr[0] = 0;
}

__global__ void scatter_kernel(const int* __restrict__ src, const int* __restrict__ dst,
                               int* __restrict__ cursor, int* __restrict__ ebuf,
                               int* __restrict__ srcp, int* __restrict__ dstp, int E, int N){
  int e = blockIdx.x*blockDim.x + threadIdx.x;
  if(e >= E + N) return;
  int d = (e < E) ? dst[e] : (e - E);
  int s = (e < E) ? src[e] : (e - E);
  int pos = atomicAdd(&cursor[d], 1);
  ebuf[pos] = e;
  srcp[pos] = s;
  dstp[pos] = d;
}

// ---------------- GAT pieces ----------------
__global__ void meansum_part_kernel(const float* __restrict__ ea, float* __restrict__ partial, int E){
  __shared__ float red[256*5];
  float loc[5] = {0.f,0.f,0.f,0.f,0.f};
  for(int e = blockIdx.x*blockDim.x + threadIdx.x; e < E; e += gridDim.x*blockDim.x){
    #pragma unroll
    for(int k = 0; k < 5; k++) loc[k] += ea[(long)e*5 + k];
  }
  #pragma unroll
  for(int k = 0; k < 5; k++) red[threadIdx.x*5 + k] = loc[k];
  __syncthreads();
  for(int off = 128; off >= 1; off >>= 1){
    if((int)threadIdx.x < off){
      #pragma unroll
      for(int k = 0; k < 5; k++)
        red[threadIdx.x*5 + k] += red[(threadIdx.x + off)*5 + k];
    }
    __syncthreads();
  }
  if(threadIdx.x < 5) partial[blockIdx.x*5 + threadIdx.x] = red[threadIdx.x];
}

__global__ void meansum_final_kernel(const float* __restrict__ partial, float* __restrict__ sum5, int nb){
  int k = threadIdx.x;
  if(k >= 5) return;
  float s = 0.f;
  for(int b = 0; b < nb; b++) s += partial[b*5 + k];
  sum5[k] = s;
}

__global__ void edgeM_kernel(const float* __restrict__ We, const float* __restrict__ ae,
                             const float* __restrict__ sum5, float* __restrict__ Mout,
                             float* __restrict__ loopOut, int H, int D, float invE){
  __shared__ float Msh[25];
  int t = threadIdx.x;
  if(t < 5*H){
    int k = t / H, hh = t % H;
    float s = 0.f;
    for(int d = 0; d < D; d++) s = fmaf(We[(long)k*H*D + hh*D + d], ae[hh*D + d], s);
    Msh[t] = s;
    Mout[t] = s;
  }
  __syncthreads();
  if(t < H){
    float s = 0.f;
    for(int k = 0; k < 5; k++) s = fmaf(sum5[k]*invE, Msh[k*H + t], s);
    loopOut[t] = s;
  }
}

// alpha in CSR order (edge-parallel, single gather pass)
__global__ void alpha_csr_kernel(const int* __restrict__ ebuf, const int* __restrict__ srcp,
                                 const int* __restrict__ dstp,
                                 const float* __restrict__ ssrc, const float* __restrict__ sdst,
                                 const float* __restrict__ eattr, const float* __restrict__ M,
                                 const float* __restrict__ loopS, float* __restrict__ alpha,
                                 int E, int N, int H){
  int p = blockIdx.x*blockDim.x + threadIdx.x;
  if(p >= E + N) return;
  int e = ebuf[p], s = srcp[p], d = dstp[p];
  float ea[5];
  if(eattr && e < E){
    #pragma unroll
    for(int k = 0; k < 5; k++) ea[k] = eattr[(long)e*5 + k];
  }
  for(int hh = 0; hh < H; hh++){
    float a = ssrc[s*H + hh] + sdst[d*H + hh];
    if(eattr){
      if(e < E){
        float es = 0.f;
        #pragma unroll
        for(int k = 0; k < 5; k++) es = fmaf(ea[k], M[k*H + hh], es);
        a += es;
      } else {
        a += loopS[hh];
      }
    }
    a = a > 0.f ? a : 0.2f*a;
    alpha[(long)p*H + hh] = a;
  }
}

// per (dst,head): softmax over contiguous CSR range, weights in place
__global__ void statsweights_kernel(const int* __restrict__ indptr,
                                    const float* __restrict__ alpha,
                                    float* __restrict__ W, int N, int H){
  int t = blockIdx.x*blockDim.x + threadIdx.x;
  if(t >= N*H) return;
  int n = t / H, hh = t - n*H;
  int b0 = indptr[n], b1 = indptr[n+1];
  float m = -1e30f;
  for(int i = b0; i < b1; i++) m = fmaxf(m, alpha[(long)i*H + hh]);
  float s = 0.f;
  for(int i = b0; i < b1; i++) s += expf(alpha[(long)i*H + hh] - m);
  float inv = 1.f / (s + 1e-16f);
  for(int i = b0; i < b1; i++)
    W[(long)i*H + hh] = expf(alpha[(long)i*H + hh] - m) * inv;
}

// one wave per node; bf16 in AND out; 2-edge unroll; u<<16 unpack (1 op saved/dword)
template<int H, int D>
__global__ __launch_bounds__(256) void aggregate_kernel(
    const int* __restrict__ indptr, const int* __restrict__ srcp,
    const float* __restrict__ W, const short* __restrict__ hfeat,
    const float* __restrict__ bias, short* __restrict__ out,
    int ldh, int ldx, int act){
  constexpr int F = H*D;
  constexpr int CH = F/2;
  constexpr int NS = (CH + 63)/64;
  const int wave = threadIdx.x >> 6, lane = threadIdx.x & 63;
  const int n = blockIdx.x*4 + wave;
  if(n >= NN) return;
  const int b0 = indptr[n], b1 = indptr[n+1];
  f32x2 acc[NS];
  int hidx[NS];
  #pragma unroll
  for(int s = 0; s < NS; s++){
    acc[s].x = 0.f; acc[s].y = 0.f;
    int c = lane + 64*s;
    hidx[s] = (c < CH) ? (2*c)/D : 0;
  }
  int i = b0;
  for(; i + 1 < b1; i += 2){
    int sv0 = srcp[i], sv1 = srcp[i+1];
    const short* hr0 = hfeat + (long)sv0*ldh;
    const short* hr1 = hfeat + (long)sv1*ldh;
    #pragma unroll
    for(int s = 0; s < NS; s++){
      int c = lane + 64*s;
      if(c < CH){
        float w0 = W[(long)i*H + hidx[s]];
        float w1 = W[(long)(i+1)*H + hidx[s]];
        unsigned u0 = *(const unsigned*)&hr0[2*c];
        unsigned u1 = *(const unsigned*)&hr1[2*c];
        acc[s].x = fmaf(w0, __uint_as_float(u0 << 16), acc[s].x);
        acc[s].y = fmaf(w0, __uint_as_float(u0 & 0xffff0000u), acc[s].y);
        acc[s].x = fmaf(w1, __uint_as_float(u1 << 16), acc[s].x);
        acc[s].y = fmaf(w1, __uint_as_float(u1 & 0xffff0000u), acc[s].y);
      }
    }
  }
  if(i < b1){
    int sv = srcp[i];
    const short* hr = hfeat + (long)sv*ldh;
    #pragma unroll
    for(int s = 0; s < NS; s++){
      int c = lane + 64*s;
      if(c < CH){
        float w = W[(long)i*H + hidx[s]];
        unsigned u = *(const unsigned*)&hr[2*c];
        acc[s].x = fmaf(w, __uint_as_float(u << 16), acc[s].x);
        acc[s].y = fmaf(w, __uint_as_float(u & 0xffff0000u), acc[s].y);
      }
    }
  }
  #pragma unroll
  for(int s = 0; s < NS; s++){
    int c = lane + 64*s;
    if(c < CH){
      int f = 2*c;
      f32x2 b = *(const f32x2*)&bias[f];
      float v0 = acc[s].x + b.x;
      float v1 = acc[s].y + b.y;
      if(act == 1){ v0 = fmaxf(v0, 0.f); v1 = fmaxf(v1, 0.f); }
      else { v0 = v0 > 0.f ? v0 : expm1f(v0); v1 = v1 > 0.f ? v1 : expm1f(v1); }
      unsigned pu = ((unsigned)(unsigned short)f2bf(v0)) |
                    (((unsigned)(unsigned short)f2bf(v1)) << 16);
      *(unsigned*)&out[(long)n*ldx + f] = pu;
    }
  }
}

// block-per-batch max pool over bf16 rows (stride 128)
__global__ __launch_bounds__(256) void pool_batch_kernel(
    const short* __restrict__ x, float* __restrict__ out){
  const int b = blockIdx.x;
  const int F = 128;
  int n0 = (int)(((long)b*NN + BB - 1) / BB);
  int n1 = (int)(((long)(b+1)*NN + BB - 1) / BB);
  if(n1 > NN) n1 = NN;
  const int f = threadIdx.x & (F-1);
  const int half = threadIdx.x >> 7;
  float m = -1e30f;
  for(int n = n0 + half; n < n1; n += 2)
    m = fmaxf(m, bf2f(x[(long)n*F + f]));
  __shared__ float red[256];
  red[threadIdx.x] = m;
  __syncthreads();
  if(half == 0)
    out[b*F + f] = fmaxf(red[threadIdx.x], red[threadIdx.x + 128]);
}

// ---------------- CNN branch ----------------
__global__ void embw_kernel(const float* __restrict__ emb, const float* __restrict__ w1,
                            float* __restrict__ embW){
  int t = blockIdx.x*blockDim.x + threadIdx.x;
  if(t >= 26*5*64) return;
  int oc = t & 63;
  int kk = (t >> 6) % 5;
  int v = t / (5*64);
  float s = 0.f;
  for(int ic = 0; ic < 128; ic++) s = fmaf(emb[v*128 + ic], w1[(oc*128 + ic)*5 + kk], s);
  embW[(v*5 + kk)*64 + oc] = s;
}

#define C1_TP 128
__global__ void conv1_kernel(const int* __restrict__ tokens, const float* __restrict__ embW,
                             const float* __restrict__ b1, short* __restrict__ c1){
  __shared__ float T[26*5*64];
  __shared__ int tok[C1_TP + 4];
  int b = blockIdx.y;
  int p0 = blockIdx.x * C1_TP;
  for(int i = threadIdx.x; i < 2080; i += 256)
    *(f32x4*)&T[i*4] = *(const f32x4*)&embW[i*4];
  int ntok = min(C1_TP + 4, LL - p0);
  for(int i = threadIdx.x; i < ntok; i += 256) tok[i] = tokens[b*LL + p0 + i];
  __syncthreads();
  int oc = threadIdx.x & 63;
  int ps = threadIdx.x >> 6;
  float bias = b1[oc];
  int np = min(C1_TP, 996 - p0);
  for(int pp = ps; pp < np; pp += 4){
    float acc = bias;
    #pragma unroll
    for(int kk = 0; kk < 5; kk++) acc += T[(tok[pp+kk]*5 + kk)*64 + oc];
    c1[((long)b*996 + p0 + pp)*64 + oc] = f2bf(fmaxf(acc, 0.f));
  }
}

__global__ __launch_bounds__(256) void conv2_mfma_kernel(
    const short* __restrict__ c1, const float* __restrict__ w2,
    const float* __restrict__ b2, unsigned* __restrict__ xt_pre){
  __shared__ short X[66*64];
  __shared__ short Bs[6*32*32];
  const int tid = threadIdx.x;
  const int b = blockIdx.y;
  const int p0 = blockIdx.x*64;
  for(int t = tid; t < 6144; t += 256){
    int ks = t >> 10, rem = t & 1023;
    int n = rem >> 5, kl = rem & 31;
    int k = ks*32 + kl;
    int kk = k >> 6, ic = k & 63;
    Bs[ks*1024 + n*32 + (((kl>>3) ^ ((n>>1)&3))<<3) + (kl&7)] = f2bf(w2[(n*64 + ic)*3 + kk]);
  }
  for(int c = tid; c < 528; c += 256){
    int r = c >> 3, s = c & 7;
    short vs[8] = {0,0,0,0,0,0,0,0};
    if(p0 + r < 996)
      *(bf16x8*)vs = *(const bf16x8*)&c1[((long)b*996 + p0 + r)*64 + s*8];
    *(bf16x8*)&X[r*64 + ((s ^ (r&7))<<3)] = *(const bf16x8*)vs;
  }
  __syncthreads();
  const int w = tid >> 6, lane = tid & 63;
  const int lrow = lane & 15, kslot = lane >> 4;
  f32x4 acc[2] = {};
  #pragma unroll
  for(int ks = 0; ks < 6; ks++){
    int kk = ks >> 1;
    int r = w*16 + lrow + kk;
    int s = ((ks&1)*4 + kslot) ^ (r & 7);
    bf16x8 a = *(const bf16x8*)&X[r*64 + (s<<3)];
    #pragma unroll
    for(int nt = 0; nt < 2; nt++){
      int n = nt*16 + lrow;
      bf16x8 bfr = *(const bf16x8*)&Bs[ks*1024 + n*32 + ((kslot ^ ((n>>1)&3))<<3)];
      acc[nt] = __builtin_amdgcn_mfma_f32_16x16x32_bf16(a, bfr, acc[nt], 0, 0, 0);
    }
  }
  #pragma unroll
  for(int nt = 0; nt < 2; nt++){
    int oc = nt*16 + lrow;
    float bias = b2[oc];
    float m = 0.f;
    #pragma unroll
    for(int rg = 0; rg < 4; rg++){
      int prow = p0 + w*16 + kslot*4 + rg;
      float v = acc[nt][rg] + bias;
      if(prow < 994) m = fmaxf(m, v);
    }
    m = fmaxf(m, __shfl_xor(m, 16, 64));
    m = fmaxf(m, __shfl_xor(m, 32, 64));
    if(kslot == 0)
      atomicMax(&xt_pre[b*32 + oc], __float_as_uint(m));
  }
}

// ---------------- head final ----------------
__global__ void head_final_kernel(const float* __restrict__ y2, const float* __restrict__ ow,
                                  const float* __restrict__ ob, float* __restrict__ out){
  int b = blockIdx.x*blockDim.x + threadIdx.x;
  if(b >= BB) return;
  float s = ob[0];
  for(int k = 0; k < 256; k++) s = fmaf(y2[b*256 + k], ow[k], s);
  out[b] = s;
}

// =======================================================================
extern "C" void kernel_launch(void* const* d_in, const int* in_sizes, int n_in,
                              void* d_out, int out_size, void* d_ws, size_t ws_size,
                              hipStream_t stream){
  const float* drug_x    = (const float*)d_in[0];
  const int*   drug_ei   = (const int*)  d_in[1];
  const int*   drug_b    = (const int*)  d_in[2];
  const int*   tokens    = (const int*)  d_in[3];
  const float* a2h_x     = (const float*)d_in[4];
  const int*   a2h_ei    = (const int*)  d_in[5];
  const float* a2h_ea    = (const float*)d_in[6];
  const int*   a2h_b     = (const int*)  d_in[7];
  const float* gat1_w    = (const float*)d_in[8];
  const float* gat1_as   = (const float*)d_in[9];
  const float* gat1_ad   = (const float*)d_in[10];
  const float* gat1_bias = (const float*)d_in[11];
  const float* gat2_w    = (const float*)d_in[12];
  const float* gat2_as   = (const float*)d_in[13];
  const float* gat2_ad   = (const float*)d_in[14];
  const float* gat2_bias = (const float*)d_in[15];
  const float* fc_g1_w   = (const float*)d_in[16];
  const float* fc_g1_b   = (const float*)d_in[17];
  const float* embed_xt  = (const float*)d_in[18];
  const float* conv1_w   = (const float*)d_in[19];
  const float* conv1_b   = (const float*)d_in[20];
  const float* conv2_w   = (const float*)d_in[21];
  const float* conv2_b   = (const float*)d_in[22];
  const float* fc_xt1_w  = (const float*)d_in[23];
  const float* fc_xt1_b  = (const float*)d_in[24];
  const float* ag1_w     = (const float*)d_in[25];
  const float* ag1_as    = (const float*)d_in[26];
  const float* ag1_ad    = (const float*)d_in[27];
  const float* ag1_le    = (const float*)d_in[28];
  const float* ag1_ae    = (const float*)d_in[29];
  const float* ag1_bias  = (const float*)d_in[30];
  const float* ag2_w     = (const float*)d_in[31];
  const float* ag2_as    = (const float*)d_in[32];
  const float* ag2_ad    = (const float*)d_in[33];
  const float* ag2_le    = (const float*)d_in[34];
  const float* ag2_ae    = (const float*)d_in[35];
  const float* ag2_bias  = (const float*)d_in[36];
  const float* afc1_w    = (const float*)d_in[37];
  const float* afc1_b    = (const float*)d_in[38];
  const float* fc1_w     = (const float*)d_in[39];
  const float* fc1_b     = (const float*)d_in[40];
  const float* fc2_w     = (const float*)d_in[41];
  const float* fc2_b     = (const float*)d_in[42];
  const float* out_w     = (const float*)d_in[43];
  const float* out_b     = (const float*)d_in[44];
  (void)drug_b; (void)a2h_b;

  // ----- workspace layout -----
  char* ws = (char*)d_ws;
  size_t off = 0;
  auto alloc = [&](size_t bytes) -> void* {
    void* p = ws + off;
    off = (off + bytes + 255) & ~(size_t)255;
    return p;
  };
  short* HB     = (short*)alloc((size_t)NN*400*2);
  short* X1     = (short*)alloc((size_t)NN*392*2);
  float* SS     = (float*)alloc((size_t)NN*5*4);
  float* SD     = (float*)alloc((size_t)NN*5*4);
  float* ALPHA  = (float*)alloc((size_t)(EE+NN)*5*4);
  float* WBUF   = (float*)alloc((size_t)(EE+NN)*5*4);
  int*   INDPTR = (int*)alloc((size_t)(NN+1)*4);
  int*   DEGA   = (int*)alloc((size_t)NN*4);
  int*   CURSOR = (int*)alloc((size_t)NN*4);
  int*   BSUM   = (int*)alloc((size_t)64*4);
  int*   EBUF   = (int*)alloc((size_t)(EE+NN)*4);
  int*   SRCP   = (int*)alloc((size_t)(EE+NN)*4);
  int*   DSTP   = (int*)alloc((size_t)(EE+NN)*4);
  float* WEXT   = (float*)alloc((size_t)390*400*4);
  float* SUMP   = (float*)alloc((size_t)256*5*4);
  float* SUM5   = (float*)alloc(64);
  float* M1     = (float*)alloc(128);
  float* LOOP1  = (float*)alloc(64);
  float* M2     = (float*)alloc(64);
  float* LOOP2  = (float*)alloc(64);
  float* EMBW   = (float*)alloc((size_t)26*5*64*4);
  unsigned* XT_PRE = (unsigned*)alloc((size_t)BB*32*4);
  float* POOLG  = (float*)alloc((size_t)BB*128*4);
  float* POOLA  = (float*)alloc((size_t)BB*128*4);
  float* XC     = (float*)alloc((size_t)BB*384*4);
  float* Y1     = (float*)alloc((size_t)BB*1024*4);
  float* Y2     = (float*)alloc((size_t)BB*256*4);
  float* PART   = (float*)alloc((size_t)8*BB*1024*4);
  (void)ws_size; (void)in_sizes; (void)n_in; (void)out_size;

  int gEN = cdiv(EE + NN, 256);
  const int NB = cdiv(NN, 1024);

  auto build_csr = [&](const int* src, const int* dst){
    zero_kernel<<<cdiv(NN,256), 256, 0, stream>>>((unsigned*)DEGA, NN);
    count_kernel<<<gEN, 256, 0, stream>>>(dst, DEGA, EE, NN);
    scan_sums_kernel<<<NB, 256, 0, stream>>>(DEGA, BSUM, NN);
    scan_bsum_kernel<<<1, 64, 0, stream>>>(BSUM, NB);
    scan_final_kernel<<<NB, 256, 0, stream>>>(DEGA, BSUM, INDPTR, CURSOR, NN);
    scatter_kernel<<<gEN, 256, 0, stream>>>(src, dst, CURSOR, EBUF, SRCP, DSTP, EE, NN);
  };

  auto run_gat = [&](const void* xin, bool xbf16, int lda, int Kin,
                     const float* W, const float* asrc, const float* adst,
                     const float* bias, int H, int D, int act,
                     const float* eattr, const float* Mmat, const float* loopS,
                     short* xout, int ldx){
    int F = H*D;
    int NE = F + 2*H;
    int ldh = (NE + 7) & ~7;
    wext_kernel<<<cdiv(Kin*NE,256), 256, 0, stream>>>(W, asrc, adst, WEXT, Kin, F, H, D);
    dim3 g(cdiv(NE,64), cdiv(NN,128));
    if(xbf16)
      gemm_mfma_bf16in_kernel<<<g, 256, 0, stream>>>((const short*)xin, lda, WEXT, HB, NN, NE, Kin, ldh);
    else
      gemm_mfma_bf16_kernel<<<g, 256, 0, stream>>>((const float*)xin, WEXT, HB, NN, NE, Kin, ldh);
    extract_scores_kernel<<<cdiv(NN*H,256), 256, 0, stream>>>(HB, SS, SD, NN, H, F, ldh);
    alpha_csr_kernel<<<gEN, 256, 0, stream>>>(EBUF, SRCP, DSTP, SS, SD, eattr, Mmat, loopS,
                                              ALPHA, EE, NN, H);
    statsweights_kernel<<<cdiv(NN*H,256), 256, 0, stream>>>(INDPTR, ALPHA, WBUF, NN, H);
    dim3 ga(cdiv(NN,4));
    if(H == 5 && D == 78)
      aggregate_kernel<5,78><<<ga, 256, 0, stream>>>(INDPTR, SRCP, WBUF, HB, bias, xout, ldh, ldx, act);
    else if(H == 5 && D == 64)
      aggregate_kernel<5,64><<<ga, 256, 0, stream>>>(INDPTR, SRCP, WBUF, HB, bias, xout, ldh, ldx, act);
    else
      aggregate_kernel<1,128><<<ga, 256, 0, stream>>>(INDPTR, SRCP, WBUF, HB, bias, xout, ldh, ldx, act);
  };

  auto run_fc = [&](const float* A, const float* Bw, const float* bias, float* C,
                    int M, int N, int K, int KS, int act, int ldc){
    if(KS == 1){
      dim3 g(cdiv(N,64), cdiv(M,32));
      if(act == 1)
        gemm_small_kernel<1><<<g, 256, 0, stream>>>(A, Bw, bias, C, M, N, K, ldc);
      else
        gemm_small_kernel<0><<<g, 256, 0, stream>>>(A, Bw, bias, C, M, N, K, ldc);
      return;
    }
    dim3 g(cdiv(N,64), cdiv(M,32), KS);
    gemm_splitk_kernel<<<g, 256, 0, stream>>>(A, Bw, PART, M, N, K, KS);
    int nout = M*N;
    if(act == 1)
      splitk_reduce_kernel<1><<<cdiv(nout,256), 256, 0, stream>>>(PART, bias, C, M, N, KS, ldc);
    else
      splitk_reduce_kernel<0><<<cdiv(nout,256), 256, 0, stream>>>(PART, bias, C, M, N, KS, ldc);
  };

  // ================= drug GAT branch =================
  build_csr(drug_ei, drug_ei + EE);
  run_gat(drug_x, false, 0, 78, gat1_w, gat1_as, gat1_ad, gat1_bias, 5, 78, /*ELU*/2,
          nullptr, nullptr, nullptr, X1, 392);
  run_gat(X1, true, 392, 390, gat2_w, gat2_as, gat2_ad, gat2_bias, 1, 128, /*ReLU*/1,
          nullptr, nullptr, nullptr, X1, 128);
  pool_batch_kernel<<<BB, 256, 0, stream>>>(X1, POOLG);
  run_fc(POOLG, fc_g1_w, fc_g1_b, XC + 0, BB, 128, 128, 1, 1, 384);

  // ================= a2h GAT branch =================
  build_csr(a2h_ei, a2h_ei + EE);
  meansum_part_kernel<<<256, 256, 0, stream>>>(a2h_ea, SUMP, EE);
  meansum_final_kernel<<<1, 64, 0, stream>>>(SUMP, SUM5, 256);
  edgeM_kernel<<<1, 64, 0, stream>>>(ag1_le, ag1_ae, SUM5, M1, LOOP1, 5, 64, 1.f/EE);
  edgeM_kernel<<<1, 64, 0, stream>>>(ag2_le, ag2_ae, SUM5, M2, LOOP2, 1, 128, 1.f/EE);
  run_gat(a2h_x, false, 0, 24, ag1_w, ag1_as, ag1_ad, ag1_bias, 5, 64, /*ELU*/2,
          a2h_ea, M1, LOOP1, X1, 320);
  run_gat(X1, true, 320, 320, ag2_w, ag2_as, ag2_ad, ag2_bias, 1, 128, /*ReLU*/1,
          a2h_ea, M2, LOOP2, X1, 128);
  pool_batch_kernel<<<BB, 256, 0, stream>>>(X1, POOLA);
  run_fc(POOLA, afc1_w, afc1_b, XC + 256, BB, 128, 128, 1, 1, 384);

  // ================= protein CNN branch =================
  embw_kernel<<<cdiv(26*5*64,256), 256, 0, stream>>>(embed_xt, conv1_w, EMBW);
  short* C1 = HB;
  conv1_kernel<<<dim3(cdiv(996, C1_TP), BB), 256, 0, stream>>>(tokens, EMBW, conv1_b, C1);
  zero_kernel<<<cdiv(BB*32,256), 256, 0, stream>>>(XT_PRE, (long)BB*32);
  conv2_mfma_kernel<<<dim3(16, BB), 256, 0, stream>>>(C1, conv2_w, conv2_b, XT_PRE);
  run_fc((const float*)XT_PRE, fc_xt1_w, fc_xt1_b, XC + 128, BB, 128, 32, 1, 0, 384);

  // ================= fusion head =================
  run_fc(XC, fc1_w, fc1_b, Y1, BB, 1024, 384, 3, 1, 1024);
  run_fc(Y1, fc2_w, fc2_b, Y2, BB, 256, 1024, 8, 1, 256);
  head_final_kernel<<<1, 256, 0, stream>>>(Y2, out_w, out_b, (float*)d_out);
}

// Round 14
// 686.848 us; speedup vs baseline: 1.1299x; 1.1299x over previous
//
#include <hip/hip_runtime.h>

#define NN 50000
#define EE 200000
#define BB 256
#define LL 1000

static inline int cdiv(int a, int b){ return (a + b - 1) / b; }

typedef __attribute__((ext_vector_type(4))) float f32x4;
typedef __attribute__((ext_vector_type(2))) float f32x2;
typedef __attribute__((ext_vector_type(8))) short bf16x8;

__device__ inline short f2bf(float f){
  unsigned u = __float_as_uint(f);
  unsigned r = u + 0x7fffu + ((u >> 16) & 1u);
  return (short)(r >> 16);
}
__device__ inline float bf2f(short s){
  return __uint_as_float(((unsigned)(unsigned short)s) << 16);
}

// ---------------- utility ----------------
__global__ void zero_kernel(unsigned* __restrict__ p, long n){
  long i = (long)blockIdx.x*blockDim.x + threadIdx.x;
  long st = (long)gridDim.x*blockDim.x;
  for(; i < n; i += st) p[i] = 0u;
}

// ---------------- small GEMM, direct ----------------
template<int ACT>
__global__ __launch_bounds__(256) void gemm_small_kernel(
    const float* __restrict__ A, const float* __restrict__ B,
    const float* __restrict__ bias, float* __restrict__ C,
    int M, int N, int K, int ldc){
  __shared__ float As[32][17];
  const int tid = threadIdx.x;
  const int col = blockIdx.x*64 + (tid & 63);
  const int rg = tid >> 6;
  const int row0 = blockIdx.y*32;
  float acc[8] = {};
  for(int kb = 0; kb < K; kb += 16){
    int kn = min(16, K - kb);
    for(int i = tid; i < 32*16; i += 256){
      int r = i >> 4, kk = i & 15;
      int gr = row0 + r;
      As[r][kk] = (gr < M && kb + kk < K) ? A[(long)gr*K + kb + kk] : 0.f;
    }
    __syncthreads();
    if(col < N){
      for(int kk = 0; kk < kn; kk++){
        float b = B[(long)(kb+kk)*N + col];
        #pragma unroll
        for(int i = 0; i < 8; i++)
          acc[i] = fmaf(As[rg*8 + i][kk], b, acc[i]);
      }
    }
    __syncthreads();
  }
  if(col < N){
    float bs = bias[col];
    #pragma unroll
    for(int i = 0; i < 8; i++){
      int r = row0 + rg*8 + i;
      if(r < M){
        float v = acc[i] + bs;
        if(ACT == 1) v = fmaxf(v, 0.f);
        C[(long)r*ldc + col] = v;
      }
    }
  }
}

// ---------------- split-K small GEMM ----------------
__global__ __launch_bounds__(256) void gemm_splitk_kernel(
    const float* __restrict__ A, const float* __restrict__ B,
    float* __restrict__ part, int M, int N, int K, int KS){
  __shared__ float As[32][17];
  const int tid = threadIdx.x;
  const int col = blockIdx.x*64 + (tid & 63);
  const int rg = tid >> 6;
  const int row0 = blockIdx.y*32;
  const int kc = (K + KS - 1) / KS;
  const int k0 = blockIdx.z * kc;
  const int k1 = min(k0 + kc, K);
  float acc[8] = {};
  for(int kb = k0; kb < k1; kb += 16){
    int kn = min(16, k1 - kb);
    for(int i = tid; i < 32*16; i += 256){
      int r = i >> 4, kk = i & 15;
      int gr = row0 + r;
      As[r][kk] = (gr < M && kb + kk < k1) ? A[(long)gr*K + kb + kk] : 0.f;
    }
    __syncthreads();
    if(col < N){
      for(int kk = 0; kk < kn; kk++){
        float b = B[(long)(kb+kk)*N + col];
        #pragma unroll
        for(int i = 0; i < 8; i++)
          acc[i] = fmaf(As[rg*8 + i][kk], b, acc[i]);
      }
    }
    __syncthreads();
  }
  if(col < N){
    #pragma unroll
    for(int i = 0; i < 8; i++){
      int r = row0 + rg*8 + i;
      if(r < M) part[((long)blockIdx.z*M + r)*N + col] = acc[i];
    }
  }
}

template<int ACT>
__global__ void splitk_reduce_kernel(const float* __restrict__ part,
                                     const float* __restrict__ bias,
                                     float* __restrict__ C,
                                     int M, int N, int KS, int ldc){
  int idx = blockIdx.x*256 + threadIdx.x;
  if(idx >= M*N) return;
  int r = idx / N, c = idx - r*N;
  float s = 0.f;
  for(int z = 0; z < KS; z++) s += part[((long)z*M + r)*N + c];
  s += bias[c];
  if(ACT == 1) s = fmaxf(s, 0.f);
  C[(long)r*ldc + c] = s;
}

// ---------------- MFMA bf16 GEMM, fp32 A input, bf16 output ----------------
__global__ __launch_bounds__(256) void gemm_mfma_bf16_kernel(
    const float* __restrict__ A, const float* __restrict__ B,
    short* __restrict__ C, int M, int N, int K, int ldc){
  __shared__ short As[128*32];
  __shared__ short Bs[64*32];
  const int tid = threadIdx.x;
  const int wave = tid >> 6, lane = tid & 63;
  const int wm = wave >> 1, wn = wave & 1;
  const int row0 = blockIdx.y*128, col0 = blockIdx.x*64;
  const int lrow = lane & 15;
  const int kslot = lane >> 4;
  const int bn = tid & 63, bs = tid >> 6;
  f32x4 acc[4][2] = {};
  for(int k0 = 0; k0 < K; k0 += 32){
    #pragma unroll
    for(int id = tid; id < 512; id += 256){
      int r = id >> 2, s = id & 3;
      int grow = row0 + r, gk = k0 + s*8;
      short vs[8];
      if(grow < M && gk + 7 < K){
        const float* p = A + (long)grow*K + gk;
        #pragma unroll
        for(int i = 0; i < 8; i += 2){
          f32x2 x = *(const f32x2*)(p + i);
          vs[i] = f2bf(x.x); vs[i+1] = f2bf(x.y);
        }
      } else {
        #pragma unroll
        for(int i = 0; i < 8; i++){
          float f = (grow < M && gk + i < K) ? A[(long)grow*K + gk + i] : 0.f;
          vs[i] = f2bf(f);
        }
      }
      *(bf16x8*)&As[r*32 + (s ^ ((r>>1)&3))*8] = *(const bf16x8*)vs;
    }
    {
      int gn = col0 + bn, gk = k0 + bs*8;
      short vs[8];
      #pragma unroll
      for(int i = 0; i < 8; i++){
        float f = (gn < N && gk + i < K) ? B[(long)(gk+i)*N + gn] : 0.f;
        vs[i] = f2bf(f);
      }
      *(bf16x8*)&Bs[bn*32 + (bs ^ ((bn>>1)&3))*8] = *(const bf16x8*)vs;
    }
    __syncthreads();
    bf16x8 af[4], bfr[2];
    #pragma unroll
    for(int mt = 0; mt < 4; mt++){
      int r = wm*64 + mt*16 + lrow;
      af[mt] = *(const bf16x8*)&As[r*32 + (kslot ^ ((r>>1)&3))*8];
    }
    #pragma unroll
    for(int nt = 0; nt < 2; nt++){
      int r = wn*32 + nt*16 + lrow;
      bfr[nt] = *(const bf16x8*)&Bs[r*32 + (kslot ^ ((r>>1)&3))*8];
    }
    #pragma unroll
    for(int mt = 0; mt < 4; mt++)
      #pragma unroll
      for(int nt = 0; nt < 2; nt++)
        acc[mt][nt] = __builtin_amdgcn_mfma_f32_16x16x32_bf16(af[mt], bfr[nt], acc[mt][nt], 0, 0, 0);
    __syncthreads();
  }
  #pragma unroll
  for(int mt = 0; mt < 4; mt++){
    #pragma unroll
    for(int nt = 0; nt < 2; nt++){
      #pragma unroll
      for(int rg = 0; rg < 4; rg++){
        int row = row0 + wm*64 + mt*16 + (lane>>4)*4 + rg;
        int col = col0 + wn*32 + nt*16 + (lane&15);
        if(row < M && col < N)
          C[(long)row*ldc + col] = f2bf(acc[mt][nt][rg]);
      }
    }
  }
}

// ---------------- MFMA bf16 GEMM, bf16 A input ----------------
__global__ __launch_bounds__(256) void gemm_mfma_bf16in_kernel(
    const short* __restrict__ A, int lda, const float* __restrict__ B,
    short* __restrict__ C, int M, int N, int K, int ldc){
  __shared__ short As[128*32];
  __shared__ short Bs[64*32];
  const int tid = threadIdx.x;
  const int wave = tid >> 6, lane = tid & 63;
  const int wm = wave >> 1, wn = wave & 1;
  const int row0 = blockIdx.y*128, col0 = blockIdx.x*64;
  const int lrow = lane & 15;
  const int kslot = lane >> 4;
  const int bn = tid & 63, bs = tid >> 6;
  f32x4 acc[4][2] = {};
  for(int k0 = 0; k0 < K; k0 += 32){
    #pragma unroll
    for(int id = tid; id < 512; id += 256){
      int r = id >> 2, s = id & 3;
      int grow = row0 + r, gk = k0 + s*8;
      short vs[8];
      if(grow < M && gk + 7 < K){
        *(bf16x8*)vs = *(const bf16x8*)&A[(long)grow*lda + gk];
      } else {
        #pragma unroll
        for(int i = 0; i < 8; i++)
          vs[i] = (grow < M && gk + i < K) ? A[(long)grow*lda + gk + i] : (short)0;
      }
      *(bf16x8*)&As[r*32 + (s ^ ((r>>1)&3))*8] = *(const bf16x8*)vs;
    }
    {
      int gn = col0 + bn, gk = k0 + bs*8;
      short vs[8];
      #pragma unroll
      for(int i = 0; i < 8; i++){
        float f = (gn < N && gk + i < K) ? B[(long)(gk+i)*N + gn] : 0.f;
        vs[i] = f2bf(f);
      }
      *(bf16x8*)&Bs[bn*32 + (bs ^ ((bn>>1)&3))*8] = *(const bf16x8*)vs;
    }
    __syncthreads();
    bf16x8 af[4], bfr[2];
    #pragma unroll
    for(int mt = 0; mt < 4; mt++){
      int r = wm*64 + mt*16 + lrow;
      af[mt] = *(const bf16x8*)&As[r*32 + (kslot ^ ((r>>1)&3))*8];
    }
    #pragma unroll
    for(int nt = 0; nt < 2; nt++){
      int r = wn*32 + nt*16 + lrow;
      bfr[nt] = *(const bf16x8*)&Bs[r*32 + (kslot ^ ((r>>1)&3))*8];
    }
    #pragma unroll
    for(int mt = 0; mt < 4; mt++)
      #pragma unroll
      for(int nt = 0; nt < 2; nt++)
        acc[mt][nt] = __builtin_amdgcn_mfma_f32_16x16x32_bf16(af[mt], bfr[nt], acc[mt][nt], 0, 0, 0);
    __syncthreads();
  }
  #pragma unroll
  for(int mt = 0; mt < 4; mt++){
    #pragma unroll
    for(int nt = 0; nt < 2; nt++){
      #pragma unroll
      for(int rg = 0; rg < 4; rg++){
        int row = row0 + wm*64 + mt*16 + (lane>>4)*4 + rg;
        int col = col0 + wn*32 + nt*16 + (lane&15);
        if(row < M && col < N)
          C[(long)row*ldc + col] = f2bf(acc[mt][nt][rg]);
      }
    }
  }
}

// Build WEXT[K][F+2H] = [W | interleaved Wa_src,Wa_dst columns]
__global__ void wext_kernel(const float* __restrict__ W, const float* __restrict__ asrc,
                            const float* __restrict__ adst, float* __restrict__ WEXT,
                            int K, int F, int H, int D){
  int NE = F + 2*H;
  int t = blockIdx.x*blockDim.x + threadIdx.x;
  if(t >= K*NE) return;
  int k = t / NE, c = t - k*NE;
  float v;
  if(c < F){
    v = W[(long)k*F + c];
  } else {
    int cc = c - F;
    int h = cc >> 1;
    const float* a = (cc & 1) ? (adst + h*D) : (asrc + h*D);
    const float* wr = W + (long)k*F + h*D;
    float s = 0.f;
    for(int d = 0; d < D; d++) s = fmaf(wr[d], a[d], s);
    v = s;
  }
  WEXT[t] = v;
}

__global__ void extract_scores_kernel(const short* __restrict__ HB, float* __restrict__ SS,
                                      float* __restrict__ SD, int N, int H, int F, int ldh){
  int t = blockIdx.x*blockDim.x + threadIdx.x;
  if(t >= N*H) return;
  int n = t / H, hh = t - n*H;
  const short* p = HB + (long)n*ldh + F + 2*hh;
  SS[t] = bf2f(p[0]);
  SD[t] = bf2f(p[1]);
}

// ---------------- CSR build ----------------
__global__ void count_kernel(const int* __restrict__ dst, int* __restrict__ deg, int E, int N){
  int e = blockIdx.x*blockDim.x + threadIdx.x;
  if(e >= E + N) return;
  int d = (e < E) ? dst[e] : (e - E);
  atomicAdd(&deg[d], 1);
}

__global__ void scan_sums_kernel(const int* __restrict__ deg, int* __restrict__ bsum, int n){
  __shared__ int red[256];
  int base = blockIdx.x*1024 + threadIdx.x*4;
  int s = 0;
  #pragma unroll
  for(int i = 0; i < 4; i++){ int idx = base + i; if(idx < n) s += deg[idx]; }
  red[threadIdx.x] = s;
  __syncthreads();
  for(int off = 128; off >= 1; off >>= 1){
    if((int)threadIdx.x < off) red[threadIdx.x] += red[threadIdx.x + off];
    __syncthreads();
  }
  if(threadIdx.x == 0) bsum[blockIdx.x] = red[0];
}

__global__ void scan_bsum_kernel(int* __restrict__ bsum, int nb){
  int lane = threadIdx.x;
  int v = (lane < nb) ? bsum[lane] : 0;
  for(int off = 1; off < 64; off <<= 1){
    int t = __shfl_up(v, off, 64);
    if(lane >= off) v += t;
  }
  int ex = __shfl_up(v, 1, 64);
  if(lane == 0) ex = 0;
  if(lane < nb) bsum[lane] = ex;
}

__global__ void scan_final_kernel(const int* __restrict__ deg, const int* __restrict__ bsum,
                                  int* __restrict__ indptr, int* __restrict__ cursor, int n){
  __shared__ int red[256];
  const int t = threadIdx.x;
  int base = blockIdx.x*1024 + t*4;
  int v[4]; int s = 0;
  #pragma unroll
  for(int i = 0; i < 4; i++){ int idx = base + i; v[i] = (idx < n) ? deg[idx] : 0; s += v[i]; }
  red[t] = s;
  __syncthreads();
  for(int off = 1; off < 256; off <<= 1){
    int val = (t >= off) ? red[t - off] : 0;
    __syncthreads();
    red[t] += val;
    __syncthreads();
  }
  int run = bsum[blockIdx.x] + ((t > 0) ? red[t-1] : 0);
  #pragma unroll
  for(int i = 0; i < 4; i++){
    int idx = base + i;
    if(idx < n){
      cursor[idx] = run;
      run += v[i];
      indptr[idx+1] = run;
    }
  }
  if(blockIdx.x == 0 && t == 0) indptr[0] = 0;
}

__global__ void scatter_kernel(const int* __restrict__ src, const int* __restrict__ dst,
                               int* __restrict__ cursor, int* __restrict__ ebuf,
                               int* __restrict__ srcp, int* __restrict__ dstp, int E, int N){
  int e = blockIdx.x*blockDim.x + threadIdx.x;
  if(e >= E + N) return;
  int d = (e < E) ? dst[e] : (e - E);
  int s = (e < E) ? src[e] : (e - E);
  int pos = atomicAdd(&cursor[d], 1);
  ebuf[pos] = e;
  srcp[pos] = s;
  dstp[pos] = d;
}

// ---------------- GAT pieces ----------------
__global__ void meansum_part_kernel(const float* __restrict__ ea, float* __restrict__ partial, int E){
  __shared__ float red[256*5];
  float loc[5] = {0.f,0.f,0.f,0.f,0.f};
  for(int e = blockIdx.x*blockDim.x + threadIdx.x; e < E; e += gridDim.x*blockDim.x){
    #pragma unroll
    for(int k = 0; k < 5; k++) loc[k] += ea[(long)e*5 + k];
  }
  #pragma unroll
  for(int k = 0; k < 5; k++) red[threadIdx.x*5 + k] = loc[k];
  __syncthreads();
  for(int off = 128; off >= 1; off >>= 1){
    if((int)threadIdx.x < off){
      #pragma unroll
      for(int k = 0; k < 5; k++)
        red[threadIdx.x*5 + k] += red[(threadIdx.x + off)*5 + k];
    }
    __syncthreads();
  }
  if(threadIdx.x < 5) partial[blockIdx.x*5 + threadIdx.x] = red[threadIdx.x];
}

__global__ void meansum_final_kernel(const float* __restrict__ partial, float* __restrict__ sum5, int nb){
  int k = threadIdx.x;
  if(k >= 5) return;
  float s = 0.f;
  for(int b = 0; b < nb; b++) s += partial[b*5 + k];
  sum5[k] = s;
}

__global__ void edgeM_kernel(const float* __restrict__ We, const float* __restrict__ ae,
                             const float* __restrict__ sum5, float* __restrict__ Mout,
                             float* __restrict__ loopOut, int H, int D, float invE){
  __shared__ float Msh[25];
  int t = threadIdx.x;
  if(t < 5*H){
    int k = t / H, hh = t % H;
    float s = 0.f;
    for(int d = 0; d < D; d++) s = fmaf(We[(long)k*H*D + hh*D + d], ae[hh*D + d], s);
    Msh[t] = s;
    Mout[t] = s;
  }
  __syncthreads();
  if(t < H){
    float s = 0.f;
    for(int k = 0; k < 5; k++) s = fmaf(sum5[k]*invE, Msh[k*H + t], s);
    loopOut[t] = s;
  }
}

// alpha in CSR order (edge-parallel, single gather pass)
__global__ void alpha_csr_kernel(const int* __restrict__ ebuf, const int* __restrict__ srcp,
                                 const int* __restrict__ dstp,
                                 const float* __restrict__ ssrc, const float* __restrict__ sdst,
                                 const float* __restrict__ eattr, const float* __restrict__ M,
                                 const float* __restrict__ loopS, float* __restrict__ alpha,
                                 int E, int N, int H){
  int p = blockIdx.x*blockDim.x + threadIdx.x;
  if(p >= E + N) return;
  int e = ebuf[p], s = srcp[p], d = dstp[p];
  float ea[5];
  if(eattr && e < E){
    #pragma unroll
    for(int k = 0; k < 5; k++) ea[k] = eattr[(long)e*5 + k];
  }
  for(int hh = 0; hh < H; hh++){
    float a = ssrc[s*H + hh] + sdst[d*H + hh];
    if(eattr){
      if(e < E){
        float es = 0.f;
        #pragma unroll
        for(int k = 0; k < 5; k++) es = fmaf(ea[k], M[k*H + hh], es);
        a += es;
      } else {
        a += loopS[hh];
      }
    }
    a = a > 0.f ? a : 0.2f*a;
    alpha[(long)p*H + hh] = a;
  }
}

// per (dst,head): softmax over contiguous CSR range, weights in place
__global__ void statsweights_kernel(const int* __restrict__ indptr,
                                    const float* __restrict__ alpha,
                                    float* __restrict__ W, int N, int H){
  int t = blockIdx.x*blockDim.x + threadIdx.x;
  if(t >= N*H) return;
  int n = t / H, hh = t - n*H;
  int b0 = indptr[n], b1 = indptr[n+1];
  float m = -1e30f;
  for(int i = b0; i < b1; i++) m = fmaxf(m, alpha[(long)i*H + hh]);
  float s = 0.f;
  for(int i = b0; i < b1; i++) s += expf(alpha[(long)i*H + hh] - m);
  float inv = 1.f / (s + 1e-16f);
  for(int i = b0; i < b1; i++)
    W[(long)i*H + hh] = expf(alpha[(long)i*H + hh] - m) * inv;
}

// one wave per node; bf16 in AND out; 2-edge unroll
template<int H, int D>
__global__ __launch_bounds__(256) void aggregate_kernel(
    const int* __restrict__ indptr, const int* __restrict__ srcp,
    const float* __restrict__ W, const short* __restrict__ hfeat,
    const float* __restrict__ bias, short* __restrict__ out,
    int ldh, int ldx, int act){
  constexpr int F = H*D;
  constexpr int CH = F/2;
  constexpr int NS = (CH + 63)/64;
  const int wave = threadIdx.x >> 6, lane = threadIdx.x & 63;
  const int n = blockIdx.x*4 + wave;
  if(n >= NN) return;
  const int b0 = indptr[n], b1 = indptr[n+1];
  f32x2 acc[NS];
  int hidx[NS];
  #pragma unroll
  for(int s = 0; s < NS; s++){
    acc[s].x = 0.f; acc[s].y = 0.f;
    int c = lane + 64*s;
    hidx[s] = (c < CH) ? (2*c)/D : 0;
  }
  int i = b0;
  for(; i + 1 < b1; i += 2){
    int sv0 = srcp[i], sv1 = srcp[i+1];
    const short* hr0 = hfeat + (long)sv0*ldh;
    const short* hr1 = hfeat + (long)sv1*ldh;
    #pragma unroll
    for(int s = 0; s < NS; s++){
      int c = lane + 64*s;
      if(c < CH){
        float w0 = W[(long)i*H + hidx[s]];
        float w1 = W[(long)(i+1)*H + hidx[s]];
        unsigned u0 = *(const unsigned*)&hr0[2*c];
        unsigned u1 = *(const unsigned*)&hr1[2*c];
        acc[s].x = fmaf(w0, __uint_as_float(u0 << 16), acc[s].x);
        acc[s].y = fmaf(w0, __uint_as_float(u0 & 0xffff0000u), acc[s].y);
        acc[s].x = fmaf(w1, __uint_as_float(u1 << 16), acc[s].x);
        acc[s].y = fmaf(w1, __uint_as_float(u1 & 0xffff0000u), acc[s].y);
      }
    }
  }
  if(i < b1){
    int sv = srcp[i];
    const short* hr = hfeat + (long)sv*ldh;
    #pragma unroll
    for(int s = 0; s < NS; s++){
      int c = lane + 64*s;
      if(c < CH){
        float w = W[(long)i*H + hidx[s]];
        unsigned u = *(const unsigned*)&hr[2*c];
        acc[s].x = fmaf(w, __uint_as_float(u << 16), acc[s].x);
        acc[s].y = fmaf(w, __uint_as_float(u & 0xffff0000u), acc[s].y);
      }
    }
  }
  #pragma unroll
  for(int s = 0; s < NS; s++){
    int c = lane + 64*s;
    if(c < CH){
      int f = 2*c;
      f32x2 b = *(const f32x2*)&bias[f];
      float v0 = acc[s].x + b.x;
      float v1 = acc[s].y + b.y;
      if(act == 1){ v0 = fmaxf(v0, 0.f); v1 = fmaxf(v1, 0.f); }
      else { v0 = v0 > 0.f ? v0 : expm1f(v0); v1 = v1 > 0.f ? v1 : expm1f(v1); }
      unsigned pu = ((unsigned)(unsigned short)f2bf(v0)) |
                    (((unsigned)(unsigned short)f2bf(v1)) << 16);
      *(unsigned*)&out[(long)n*ldx + f] = pu;
    }
  }
}

// block-per-batch max pool over bf16 rows (stride 128)
__global__ __launch_bounds__(256) void pool_batch_kernel(
    const short* __restrict__ x, float* __restrict__ out){
  const int b = blockIdx.x;
  const int F = 128;
  int n0 = (int)(((long)b*NN + BB - 1) / BB);
  int n1 = (int)(((long)(b+1)*NN + BB - 1) / BB);
  if(n1 > NN) n1 = NN;
  const int f = threadIdx.x & (F-1);
  const int half = threadIdx.x >> 7;
  float m = -1e30f;
  for(int n = n0 + half; n < n1; n += 2)
    m = fmaxf(m, bf2f(x[(long)n*F + f]));
  __shared__ float red[256];
  red[threadIdx.x] = m;
  __syncthreads();
  if(half == 0)
    out[b*F + f] = fmaxf(red[threadIdx.x], red[threadIdx.x + 128]);
}

// ---------------- CNN branch ----------------
__global__ void embw_kernel(const float* __restrict__ emb, const float* __restrict__ w1,
                            float* __restrict__ embW){
  int t = blockIdx.x*blockDim.x + threadIdx.x;
  if(t >= 26*5*64) return;
  int oc = t & 63;
  int kk = (t >> 6) % 5;
  int v = t / (5*64);
  float s = 0.f;
  for(int ic = 0; ic < 128; ic++) s = fmaf(emb[v*128 + ic], w1[(oc*128 + ic)*5 + kk], s);
  embW[(v*5 + kk)*64 + oc] = s;
}

#define C1_TP 128
__global__ void conv1_kernel(const int* __restrict__ tokens, const float* __restrict__ embW,
                             const float* __restrict__ b1, short* __restrict__ c1){
  __shared__ float T[26*5*64];
  __shared__ int tok[C1_TP + 4];
  int b = blockIdx.y;
  int p0 = blockIdx.x * C1_TP;
  for(int i = threadIdx.x; i < 2080; i += 256)
    *(f32x4*)&T[i*4] = *(const f32x4*)&embW[i*4];
  int ntok = min(C1_TP + 4, LL - p0);
  for(int i = threadIdx.x; i < ntok; i += 256) tok[i] = tokens[b*LL + p0 + i];
  __syncthreads();
  int oc = threadIdx.x & 63;
  int ps = threadIdx.x >> 6;
  float bias = b1[oc];
  int np = min(C1_TP, 996 - p0);
  for(int pp = ps; pp < np; pp += 4){
    float acc = bias;
    #pragma unroll
    for(int kk = 0; kk < 5; kk++) acc += T[(tok[pp+kk]*5 + kk)*64 + oc];
    c1[((long)b*996 + p0 + pp)*64 + oc] = f2bf(fmaxf(acc, 0.f));
  }
}

__global__ __launch_bounds__(256) void conv2_mfma_kernel(
    const short* __restrict__ c1, const float* __restrict__ w2,
    const float* __restrict__ b2, unsigned* __restrict__ xt_pre){
  __shared__ short X[66*64];
  __shared__ short Bs[6*32*32];
  const int tid = threadIdx.x;
  const int b = blockIdx.y;
  const int p0 = blockIdx.x*64;
  for(int t = tid; t < 6144; t += 256){
    int ks = t >> 10, rem = t & 1023;
    int n = rem >> 5, kl = rem & 31;
    int k = ks*32 + kl;
    int kk = k >> 6, ic = k & 63;
    Bs[ks*1024 + n*32 + (((kl>>3) ^ ((n>>1)&3))<<3) + (kl&7)] = f2bf(w2[(n*64 + ic)*3 + kk]);
  }
  for(int c = tid; c < 528; c += 256){
    int r = c >> 3, s = c & 7;
    short vs[8] = {0,0,0,0,0,0,0,0};
    if(p0 + r < 996)
      *(bf16x8*)vs = *(const bf16x8*)&c1[((long)b*996 + p0 + r)*64 + s*8];
    *(bf16x8*)&X[r*64 + ((s ^ (r&7))<<3)] = *(const bf16x8*)vs;
  }
  __syncthreads();
  const int w = tid >> 6, lane = tid & 63;
  const int lrow = lane & 15, kslot = lane >> 4;
  f32x4 acc[2] = {};
  #pragma unroll
  for(int ks = 0; ks < 6; ks++){
    int kk = ks >> 1;
    int r = w*16 + lrow + kk;
    int s = ((ks&1)*4 + kslot) ^ (r & 7);
    bf16x8 a = *(const bf16x8*)&X[r*64 + (s<<3)];
    #pragma unroll
    for(int nt = 0; nt < 2; nt++){
      int n = nt*16 + lrow;
      bf16x8 bfr = *(const bf16x8*)&Bs[ks*1024 + n*32 + ((kslot ^ ((n>>1)&3))<<3)];
      acc[nt] = __builtin_amdgcn_mfma_f32_16x16x32_bf16(a, bfr, acc[nt], 0, 0, 0);
    }
  }
  #pragma unroll
  for(int nt = 0; nt < 2; nt++){
    int oc = nt*16 + lrow;
    float bias = b2[oc];
    float m = 0.f;
    #pragma unroll
    for(int rg = 0; rg < 4; rg++){
      int prow = p0 + w*16 + kslot*4 + rg;
      float v = acc[nt][rg] + bias;
      if(prow < 994) m = fmaxf(m, v);
    }
    m = fmaxf(m, __shfl_xor(m, 16, 64));
    m = fmaxf(m, __shfl_xor(m, 32, 64));
    if(kslot == 0)
      atomicMax(&xt_pre[b*32 + oc], __float_as_uint(m));
  }
}

// ---------------- head final ----------------
__global__ void head_final_kernel(const float* __restrict__ y2, const float* __restrict__ ow,
                                  const float* __restrict__ ob, float* __restrict__ out){
  int b = blockIdx.x*blockDim.x + threadIdx.x;
  if(b >= BB) return;
  float s = ob[0];
  for(int k = 0; k < 256; k++) s = fmaf(y2[b*256 + k], ow[k], s);
  out[b] = s;
}

// =======================================================================
extern "C" void kernel_launch(void* const* d_in, const int* in_sizes, int n_in,
                              void* d_out, int out_size, void* d_ws, size_t ws_size,
                              hipStream_t stream){
  const float* drug_x    = (const float*)d_in[0];
  const int*   drug_ei   = (const int*)  d_in[1];
  const int*   drug_b    = (const int*)  d_in[2];
  const int*   tokens    = (const int*)  d_in[3];
  const float* a2h_x     = (const float*)d_in[4];
  const int*   a2h_ei    = (const int*)  d_in[5];
  const float* a2h_ea    = (const float*)d_in[6];
  const int*   a2h_b     = (const int*)  d_in[7];
  const float* gat1_w    = (const float*)d_in[8];
  const float* gat1_as   = (const float*)d_in[9];
  const float* gat1_ad   = (const float*)d_in[10];
  const float* gat1_bias = (const float*)d_in[11];
  const float* gat2_w    = (const float*)d_in[12];
  const float* gat2_as   = (const float*)d_in[13];
  const float* gat2_ad   = (const float*)d_in[14];
  const float* gat2_bias = (const float*)d_in[15];
  const float* fc_g1_w   = (const float*)d_in[16];
  const float* fc_g1_b   = (const float*)d_in[17];
  const float* embed_xt  = (const float*)d_in[18];
  const float* conv1_w   = (const float*)d_in[19];
  const float* conv1_b   = (const float*)d_in[20];
  const float* conv2_w   = (const float*)d_in[21];
  const float* conv2_b   = (const float*)d_in[22];
  const float* fc_xt1_w  = (const float*)d_in[23];
  const float* fc_xt1_b  = (const float*)d_in[24];
  const float* ag1_w     = (const float*)d_in[25];
  const float* ag1_as    = (const float*)d_in[26];
  const float* ag1_ad    = (const float*)d_in[27];
  const float* ag1_le    = (const float*)d_in[28];
  const float* ag1_ae    = (const float*)d_in[29];
  const float* ag1_bias  = (const float*)d_in[30];
  const float* ag2_w     = (const float*)d_in[31];
  const float* ag2_as    = (const float*)d_in[32];
  const float* ag2_ad    = (const float*)d_in[33];
  const float* ag2_le    = (const float*)d_in[34];
  const float* ag2_ae    = (const float*)d_in[35];
  const float* ag2_bias  = (const float*)d_in[36];
  const float* afc1_w    = (const float*)d_in[37];
  const float* afc1_b    = (const float*)d_in[38];
  const float* fc1_w     = (const float*)d_in[39];
  const float* fc1_b     = (const float*)d_in[40];
  const float* fc2_w     = (const float*)d_in[41];
  const float* fc2_b     = (const float*)d_in[42];
  const float* out_w     = (const float*)d_in[43];
  const float* out_b     = (const float*)d_in[44];
  (void)drug_b; (void)a2h_b;

  // ----- workspace layout -----
  char* ws = (char*)d_ws;
  size_t off = 0;
  auto alloc = [&](size_t bytes) -> void* {
    void* p = ws + off;
    off = (off + bytes + 255) & ~(size_t)255;
    return p;
  };
  short* HB     = (short*)alloc((size_t)NN*400*2);
  short* X1     = (short*)alloc((size_t)NN*392*2);
  float* SS     = (float*)alloc((size_t)NN*5*4);
  float* SD     = (float*)alloc((size_t)NN*5*4);
  float* ALPHA  = (float*)alloc((size_t)(EE+NN)*5*4);
  float* WBUF   = (float*)alloc((size_t)(EE+NN)*5*4);
  int*   INDPTR = (int*)alloc((size_t)(NN+1)*4);
  int*   DEGA   = (int*)alloc((size_t)NN*4);
  int*   CURSOR = (int*)alloc((size_t)NN*4);
  int*   BSUM   = (int*)alloc((size_t)64*4);
  int*   EBUF   = (int*)alloc((size_t)(EE+NN)*4);
  int*   SRCP   = (int*)alloc((size_t)(EE+NN)*4);
  int*   DSTP   = (int*)alloc((size_t)(EE+NN)*4);
  float* WEXT   = (float*)alloc((size_t)390*400*4);
  float* SUMP   = (float*)alloc((size_t)256*5*4);
  float* SUM5   = (float*)alloc(64);
  float* M1     = (float*)alloc(128);
  float* LOOP1  = (float*)alloc(64);
  float* M2     = (float*)alloc(64);
  float* LOOP2  = (float*)alloc(64);
  float* EMBW   = (float*)alloc((size_t)26*5*64*4);
  unsigned* XT_PRE = (unsigned*)alloc((size_t)BB*32*4);
  float* POOLG  = (float*)alloc((size_t)BB*128*4);
  float* POOLA  = (float*)alloc((size_t)BB*128*4);
  float* XC     = (float*)alloc((size_t)BB*384*4);
  float* Y1     = (float*)alloc((size_t)BB*1024*4);
  float* Y2     = (float*)alloc((size_t)BB*256*4);
  float* PART   = (float*)alloc((size_t)16*BB*1024*4);   // split-K partials (16 MB)
  (void)ws_size; (void)in_sizes; (void)n_in; (void)out_size;

  int gEN = cdiv(EE + NN, 256);
  const int NB = cdiv(NN, 1024);

  auto build_csr = [&](const int* src, const int* dst){
    zero_kernel<<<cdiv(NN,256), 256, 0, stream>>>((unsigned*)DEGA, NN);
    count_kernel<<<gEN, 256, 0, stream>>>(dst, DEGA, EE, NN);
    scan_sums_kernel<<<NB, 256, 0, stream>>>(DEGA, BSUM, NN);
    scan_bsum_kernel<<<1, 64, 0, stream>>>(BSUM, NB);
    scan_final_kernel<<<NB, 256, 0, stream>>>(DEGA, BSUM, INDPTR, CURSOR, NN);
    scatter_kernel<<<gEN, 256, 0, stream>>>(src, dst, CURSOR, EBUF, SRCP, DSTP, EE, NN);
  };

  auto run_gat = [&](const void* xin, bool xbf16, int lda, int Kin,
                     const float* W, const float* asrc, const float* adst,
                     const float* bias, int H, int D, int act,
                     const float* eattr, const float* Mmat, const float* loopS,
                     short* xout, int ldx){
    int F = H*D;
    int NE = F + 2*H;
    int ldh = (NE + 7) & ~7;
    wext_kernel<<<cdiv(Kin*NE,256), 256, 0, stream>>>(W, asrc, adst, WEXT, Kin, F, H, D);
    dim3 g(cdiv(NE,64), cdiv(NN,128));
    if(xbf16)
      gemm_mfma_bf16in_kernel<<<g, 256, 0, stream>>>((const short*)xin, lda, WEXT, HB, NN, NE, Kin, ldh);
    else
      gemm_mfma_bf16_kernel<<<g, 256, 0, stream>>>((const float*)xin, WEXT, HB, NN, NE, Kin, ldh);
    extract_scores_kernel<<<cdiv(NN*H,256), 256, 0, stream>>>(HB, SS, SD, NN, H, F, ldh);
    alpha_csr_kernel<<<gEN, 256, 0, stream>>>(EBUF, SRCP, DSTP, SS, SD, eattr, Mmat, loopS,
                                              ALPHA, EE, NN, H);
    statsweights_kernel<<<cdiv(NN*H,256), 256, 0, stream>>>(INDPTR, ALPHA, WBUF, NN, H);
    dim3 ga(cdiv(NN,4));
    if(H == 5 && D == 78)
      aggregate_kernel<5,78><<<ga, 256, 0, stream>>>(INDPTR, SRCP, WBUF, HB, bias, xout, ldh, ldx, act);
    else if(H == 5 && D == 64)
      aggregate_kernel<5,64><<<ga, 256, 0, stream>>>(INDPTR, SRCP, WBUF, HB, bias, xout, ldh, ldx, act);
    else
      aggregate_kernel<1,128><<<ga, 256, 0, stream>>>(INDPTR, SRCP, WBUF, HB, bias, xout, ldh, ldx, act);
  };

  auto run_fc = [&](const float* A, const float* Bw, const float* bias, float* C,
                    int M, int N, int K, int KS, int act, int ldc){
    if(KS == 1){
      dim3 g(cdiv(N,64), cdiv(M,32));
      if(act == 1)
        gemm_small_kernel<1><<<g, 256, 0, stream>>>(A, Bw, bias, C, M, N, K, ldc);
      else
        gemm_small_kernel<0><<<g, 256, 0, stream>>>(A, Bw, bias, C, M, N, K, ldc);
      return;
    }
    dim3 g(cdiv(N,64), cdiv(M,32), KS);
    gemm_splitk_kernel<<<g, 256, 0, stream>>>(A, Bw, PART, M, N, K, KS);
    int nout = M*N;
    if(act == 1)
      splitk_reduce_kernel<1><<<cdiv(nout,256), 256, 0, stream>>>(PART, bias, C, M, N, KS, ldc);
    else
      splitk_reduce_kernel<0><<<cdiv(nout,256), 256, 0, stream>>>(PART, bias, C, M, N, KS, ldc);
  };

  // ================= drug GAT branch =================
  build_csr(drug_ei, drug_ei + EE);
  run_gat(drug_x, false, 0, 78, gat1_w, gat1_as, gat1_ad, gat1_bias, 5, 78, /*ELU*/2,
          nullptr, nullptr, nullptr, X1, 392);
  run_gat(X1, true, 392, 390, gat2_w, gat2_as, gat2_ad, gat2_bias, 1, 128, /*ReLU*/1,
          nullptr, nullptr, nullptr, X1, 128);
  pool_batch_kernel<<<BB, 256, 0, stream>>>(X1, POOLG);
  run_fc(POOLG, fc_g1_w, fc_g1_b, XC + 0, BB, 128, 128, 4, 1, 384);

  // ================= a2h GAT branch =================
  build_csr(a2h_ei, a2h_ei + EE);
  meansum_part_kernel<<<256, 256, 0, stream>>>(a2h_ea, SUMP, EE);
  meansum_final_kernel<<<1, 64, 0, stream>>>(SUMP, SUM5, 256);
  edgeM_kernel<<<1, 64, 0, stream>>>(ag1_le, ag1_ae, SUM5, M1, LOOP1, 5, 64, 1.f/EE);
  edgeM_kernel<<<1, 64, 0, stream>>>(ag2_le, ag2_ae, SUM5, M2, LOOP2, 1, 128, 1.f/EE);
  run_gat(a2h_x, false, 0, 24, ag1_w, ag1_as, ag1_ad, ag1_bias, 5, 64, /*ELU*/2,
          a2h_ea, M1, LOOP1, X1, 320);
  run_gat(X1, true, 320, 320, ag2_w, ag2_as, ag2_ad, ag2_bias, 1, 128, /*ReLU*/1,
          a2h_ea, M2, LOOP2, X1, 128);
  pool_batch_kernel<<<BB, 256, 0, stream>>>(X1, POOLA);
  run_fc(POOLA, afc1_w, afc1_b, XC + 256, BB, 128, 128, 4, 1, 384);

  // ================= protein CNN branch =================
  embw_kernel<<<cdiv(26*5*64,256), 256, 0, stream>>>(embed_xt, conv1_w, EMBW);
  short* C1 = HB;
  conv1_kernel<<<dim3(cdiv(996, C1_TP), BB), 256, 0, stream>>>(tokens, EMBW, conv1_b, C1);
  zero_kernel<<<cdiv(BB*32,256), 256, 0, stream>>>(XT_PRE, (long)BB*32);
  conv2_mfma_kernel<<<dim3(16, BB), 256, 0, stream>>>(C1, conv2_w, conv2_b, XT_PRE);
  run_fc((const float*)XT_PRE, fc_xt1_w, fc_xt1_b, XC + 128, BB, 128, 32, 1, 0, 384);

  // ================= fusion head =================
  run_fc(XC, fc1_w, fc1_b, Y1, BB, 1024, 384, 12, 1, 1024);
  run_fc(Y1, fc2_w, fc2_b, Y2, BB, 256, 1024, 16, 1, 256);
  head_final_kernel<<<1, 256, 0, stream>>>(Y2, out_w, out_b, (float*)d_out);
}